// Round 2
// baseline (220.324 us; speedup 1.0000x reference)
//
#include <hip/hip_runtime.h>
#include <math.h>

#define Lq 1024
#define Hq 8
#define Eq 64
#define LDW 72              // staging row length (bf16 elems); 144 B rows stay 16B-aligned
#define PTW 40              // P^T row length (bf16 elems); 80 B rows, 16B-aligned
#define KV_SH (64 * LDW)    // shorts per K (or V^T) array = 4608
#define BUF_SH (2 * KV_SH)  // shorts per staging buffer (K + V^T) = 9216
#define PT_OFS (2 * BUF_SH) // shorts: start of per-wave P^T scratch = 18432

// slot -> source head: _PERM=[6,2,1,7,3,0,5,4]; slots 0..6 = series {2,1,7,3,0,5,4}, slot 7 = cross head 6
#define SRC_HEAD_PACKED 0x64503712u

typedef __bf16 bf16_t;
typedef __bf16 bf16x8 __attribute__((ext_vector_type(8)));
typedef __bf16 bf16x4 __attribute__((ext_vector_type(4)));
typedef float floatx4 __attribute__((ext_vector_type(4)));

__device__ __forceinline__ bf16x8 cvt8(const float4 a, const float4 b) {
    bf16x8 r;
    r[0] = (bf16_t)a.x; r[1] = (bf16_t)a.y; r[2] = (bf16_t)a.z; r[3] = (bf16_t)a.w;
    r[4] = (bf16_t)b.x; r[5] = (bf16_t)b.y; r[6] = (bf16_t)b.z; r[7] = (bf16_t)b.w;
    return r;
}
__device__ __forceinline__ bf16x4 cvt4(const float4 a) {
    bf16x4 r;
    r[0] = (bf16_t)a.x; r[1] = (bf16_t)a.y; r[2] = (bf16_t)a.z; r[3] = (bf16_t)a.w;
    return r;
}

// 16 waves: tb = wv>>3 -> tile (0 = pA, 1 = pB); kh = (wv>>2)&1 -> key half; wq = wv&3 -> q-row group.
// Each wave keeps a partial online softmax over its key half; merged once at the end.
__global__ __launch_bounds__(1024, 8)
void attn_mfma(const float* __restrict__ Q, const float* __restrict__ Ks,
               const float* __restrict__ KTs, const float* __restrict__ Vs,
               const float* __restrict__ VTs, float* __restrict__ out) {
    // grid = (slot, b, p): linear id % 8 == slot -> one slot per XCD -> K/V L2 reuse
    const int slot = blockIdx.x;
    const int b    = blockIdx.y;
    const int p    = blockIdx.z;            // pair: tiles pA=p (small), pB=15-p (large)
    const int h    = (SRC_HEAD_PACKED >> (slot * 4)) & 0xF;
    const float* __restrict__ Kp = (slot == 7) ? KTs : Ks;
    const float* __restrict__ Vp = (slot == 7) ? VTs : Vs;
    const int pA = p, pB = 15 - p;

    const int tid  = threadIdx.x;
    const int wv   = tid >> 6;              // 0..15
    const int lane = tid & 63;
    const int ln16 = lane & 15;
    const int quad = lane >> 4;
    const int wq   = wv & 3;                // q-row group
    const int kh   = (wv >> 2) & 1;         // key half
    const int tb   = wv >> 3;               // tile select
    const int pT   = tb ? pB : pA;

    __shared__ alignas(16) unsigned short smem[PT_OFS + 16 * 16 * PTW]; // 57344 B
    unsigned short* ptp = smem + PT_OFS + wv * 16 * PTW;

    // ---- Q fragment for this wave's tile (B operand [n=qrow][k=e]); fold scale*log2e ----
    const float qs = 0.125f * 1.44269504f;
    bf16x8 qf[2];
    {
        const int r = pT * 64 + wq * 16 + ln16;
        const float* qa = Q + (((size_t)b * Lq + r) * Hq + h) * Eq + quad * 8;
        #pragma unroll
        for (int ec = 0; ec < 2; ++ec) {
            float4 f0 = ((const float4*)(qa + ec * 32))[0];
            float4 f1 = ((const float4*)(qa + ec * 32))[1];
            f0.x*=qs; f0.y*=qs; f0.z*=qs; f0.w*=qs;
            f1.x*=qs; f1.y*=qs; f1.z*=qs; f1.w*=qs;
            qf[ec] = cvt8(f0, f1);
        }
    }

    floatx4 O[4];
    #pragma unroll
    for (int i = 0; i < 4; ++i) O[i] = (floatx4){0, 0, 0, 0};
    // finite sentinel (NOT -inf): an all-masked key-half must not produce inf-inf
    float m = -1e30f, l = 0.f;

    // staging (1024 threads: 4 K-floats + 4 V-floats each)
    float4 kq;
    float  vq[4];
    const int kj = tid >> 4, kc = (tid & 15) * 4;  // K: row kj, cols kc..kc+3
    const int vd = lane,     vkg = (tid >> 6) * 4; // V^T: dim vd, keys vkg..vkg+3

    auto load_tile = [&](int kt) {
        kq = *(const float4*)(Kp + (((size_t)b * Lq + kt * 64 + kj) * Hq + h) * Eq + kc);
        const float* vb = Vp + (((size_t)b * Lq + kt * 64 + vkg) * Hq + h) * Eq + vd;
        #pragma unroll
        for (int i = 0; i < 4; ++i) vq[i] = vb[(size_t)i * (Hq * Eq)];
    };
    auto stage = [&](int buf) {
        unsigned short* base = smem + buf * BUF_SH;
        *(bf16x4*)&base[kj * LDW + kc] = cvt4(kq);
        float4 vv; vv.x = vq[0]; vv.y = vq[1]; vv.z = vq[2]; vv.w = vq[3];
        *(bf16x4*)&base[KV_SH + vd * LDW + vkg] = cvt4(vv);
    };

    load_tile(0);
    stage(0);
    load_tile(1);   // pB >= 8, always valid

    for (int kt = 0; kt <= pB; ++kt) {
        __syncthreads();   // buf[kt&1] staged & visible; prior reads of buf[(kt+1)&1] done
        if (kt <= pT) {
            const unsigned short* base = smem + (kt & 1) * BUF_SH;
            bf16x8 kf[2][2], vf[4];
            #pragma unroll
            for (int c = 0; c < 2; ++c) {
                kf[c][0] = *(const bf16x8*)&base[((kh * 2 + c) * 16 + ln16) * LDW + quad * 8];
                kf[c][1] = *(const bf16x8*)&base[((kh * 2 + c) * 16 + ln16) * LDW + 32 + quad * 8];
            }
            #pragma unroll
            for (int c = 0; c < 4; ++c)
                vf[c] = *(const bf16x8*)&base[KV_SH + (c * 16 + ln16) * LDW + kh * 32 + quad * 8];

            // S^T chunk (32 keys x 16 qrows): col(ln16)=qrow, row(quad*4+r)=key-in-half
            floatx4 s[2];
            #pragma unroll
            for (int nc = 0; nc < 2; ++nc) {
                floatx4 acc = (floatx4){0, 0, 0, 0};
                acc = __builtin_amdgcn_mfma_f32_16x16x32_bf16(kf[nc][0], qf[0], acc, 0, 0, 0);
                acc = __builtin_amdgcn_mfma_f32_16x16x32_bf16(kf[nc][1], qf[1], acc, 0, 0, 0);
                s[nc] = acc;
            }
            if (kt == pT) {
                const int rin = wq * 16 + ln16;
                #pragma unroll
                for (int nc = 0; nc < 2; ++nc)
                    #pragma unroll
                    for (int r = 0; r < 4; ++r)
                        if (kh * 32 + nc * 16 + quad * 4 + r > rin) s[nc][r] = -INFINITY;
            }
            // partial row max over this key half
            float mn = s[0][0];
            #pragma unroll
            for (int nc = 0; nc < 2; ++nc)
                #pragma unroll
                for (int r = 0; r < 4; ++r) mn = fmaxf(mn, s[nc][r]);
            mn = fmaxf(mn, __shfl_xor(mn, 16, 64));
            mn = fmaxf(mn, __shfl_xor(mn, 32, 64));
            mn = fmaxf(mn, m);                       // m >= -1e30 keeps mn finite
            const float alpha = __builtin_amdgcn_exp2f(m - mn);
            m = mn;
            float ps = 0.f;
            float pv[2][4];
            #pragma unroll
            for (int nc = 0; nc < 2; ++nc)
                #pragma unroll
                for (int r = 0; r < 4; ++r) {
                    pv[nc][r] = __builtin_amdgcn_exp2f(s[nc][r] - mn);
                    ps += pv[nc][r];
                }
            ps += __shfl_xor(ps, 16, 64);
            ps += __shfl_xor(ps, 32, 64);
            l = l * alpha + ps;
            #pragma unroll
            for (int dc = 0; dc < 4; ++dc) O[dc] *= alpha;
            // P^T -> per-wave LDS (2 x b64), then one b128 B-frag read
            #pragma unroll
            for (int nc = 0; nc < 2; ++nc) {
                bf16x4 pk;
                pk[0] = (bf16_t)pv[nc][0]; pk[1] = (bf16_t)pv[nc][1];
                pk[2] = (bf16_t)pv[nc][2]; pk[3] = (bf16_t)pv[nc][3];
                *(bf16x4*)&ptp[ln16 * PTW + nc * 16 + quad * 4] = pk;
            }
            bf16x8 pf = *(const bf16x8*)&ptp[ln16 * PTW + quad * 8];
            // O^T += V^T[:, key-half] P^T
            #pragma unroll
            for (int dc = 0; dc < 4; ++dc)
                O[dc] = __builtin_amdgcn_mfma_f32_16x16x32_bf16(vf[dc], pf, O[dc], 0, 0, 0);
        }
        if (kt < pB) {
            stage((kt + 1) & 1);               // write other buffer (readers finished pre-barrier)
            if (kt + 1 < pB) load_tile(kt + 2); // prefetch a full iteration ahead
        }
    }

    // ---- merge key halves + epilogue (staging LDS dead; both tiles in parallel) ----
    __syncthreads();
    float* mb = (float*)smem + tb * 4608;   // 4608 floats = 18432 B per tile region
    if (kh) {
        float* dst = mb + (wq * 64 + lane) * 18;
        #pragma unroll
        for (int dc = 0; dc < 4; ++dc) {
            *(float2*)(dst + dc * 4)     = make_float2(O[dc][0], O[dc][1]);
            *(float2*)(dst + dc * 4 + 2) = make_float2(O[dc][2], O[dc][3]);
        }
        dst[16] = m; dst[17] = l;
    }
    __syncthreads();
    if (!kh) {
        const float* src = mb + (wq * 64 + lane) * 18;
        const float m1 = src[16], l1 = src[17];
        const float mm = fmaxf(m, m1);
        const float a0 = __builtin_amdgcn_exp2f(m - mm);
        const float a1 = __builtin_amdgcn_exp2f(m1 - mm);
        const float inv = 1.0f / (l * a0 + l1 * a1);
        const int row = pT * 64 + wq * 16 + ln16;
        float* op = out + (((size_t)b * Lq + row) * Hq + slot) * Eq + quad * 4;
        #pragma unroll
        for (int dc = 0; dc < 4; ++dc) {
            float4 o;
            o.x = (O[dc][0] * a0 + src[dc * 4 + 0] * a1) * inv;
            o.y = (O[dc][1] * a0 + src[dc * 4 + 1] * a1) * inv;
            o.z = (O[dc][2] * a0 + src[dc * 4 + 2] * a1) * inv;
            o.w = (O[dc][3] * a0 + src[dc * 4 + 3] * a1) * inv;
            *(float4*)(op + dc * 16) = o;
        }
    }
}

extern "C" void kernel_launch(void* const* d_in, const int* in_sizes, int n_in,
                              void* d_out, int out_size, void* d_ws, size_t ws_size,
                              hipStream_t stream) {
    const float* queries = (const float*)d_in[0];
    const float* keys    = (const float*)d_in[1];
    const float* keysT   = (const float*)d_in[2];
    const float* values  = (const float*)d_in[3];
    const float* valuesT = (const float*)d_in[4];
    float* out = (float*)d_out;

    dim3 grid(Hq, 8, 8);   // (slot, batch, pair): id%8==slot -> slot-per-XCD L2 grouping
    dim3 block(1024);
    attn_mfma<<<grid, block, 0, stream>>>(queries, keys, keysT, values, valuesT, out);
}

// Round 3
// 206.402 us; speedup vs baseline: 1.0674x; 1.0674x over previous
//
#include <hip/hip_runtime.h>
#include <math.h>

#define Lq 1024
#define Hq 8
#define Eq 64
#define LDW 72   // staging row length (bf16 elems); 144 B rows stay 16B-aligned
#define PTW 40   // P^T row length (bf16 elems); 80 B rows, 16B-aligned

// slot -> source head: _PERM=[6,2,1,7,3,0,5,4]; slots 0..6 = series {2,1,7,3,0,5,4}, slot 7 = cross head 6
#define SRC_HEAD_PACKED 0x64503712u

typedef __bf16 bf16_t;
typedef __bf16 bf16x8 __attribute__((ext_vector_type(8)));
typedef __bf16 bf16x4 __attribute__((ext_vector_type(4)));
typedef float floatx4 __attribute__((ext_vector_type(4)));

__device__ __forceinline__ bf16x8 cvt8(const float4 a, const float4 b) {
    bf16x8 r;
    r[0] = (bf16_t)a.x; r[1] = (bf16_t)a.y; r[2] = (bf16_t)a.z; r[3] = (bf16_t)a.w;
    r[4] = (bf16_t)b.x; r[5] = (bf16_t)b.y; r[6] = (bf16_t)b.z; r[7] = (bf16_t)b.w;
    return r;
}

// 8 waves: wq = wv&3 -> q-row group (16 rows), kh = wv>>2 -> key half (32 keys).
// One q-tile per block; each wave keeps a partial online softmax over its key half.
__global__ __launch_bounds__(512, 8)
void attn_mfma(const float* __restrict__ Q, const float* __restrict__ Ks,
               const float* __restrict__ KTs, const float* __restrict__ Vs,
               const float* __restrict__ VTs, float* __restrict__ out) {
    // grid = (slot, b, z): linear id % 8 == slot -> one slot per XCD -> K/V L2 reuse
    const int slot = blockIdx.x;
    const int b    = blockIdx.y;
    const int qt   = 15 - blockIdx.z;       // longest blocks dispatched first
    const int h    = (SRC_HEAD_PACKED >> (slot * 4)) & 0xF;
    const float* __restrict__ Kp = (slot == 7) ? KTs : Ks;
    const float* __restrict__ Vp = (slot == 7) ? VTs : Vs;

    const int tid  = threadIdx.x;
    const int wv   = tid >> 6;              // 0..7
    const int lane = tid & 63;
    const int ln16 = lane & 15;
    const int quad = lane >> 4;
    const int wq   = wv & 3;                // q-row group
    const int kh   = wv >> 2;               // key half

    __shared__ alignas(16) unsigned short smem[64 * LDW * 2 + 8 * 16 * PTW]; // 28672 B
    unsigned short (*k_lds)[LDW]  = (unsigned short (*)[LDW])smem;             // K[key][e]
    unsigned short (*vt_lds)[LDW] = (unsigned short (*)[LDW])(smem + 64 * LDW);// V^T[d][key]
    unsigned short (*pt)[PTW]     = (unsigned short (*)[PTW])(smem + 2 * 64 * LDW + wv * 16 * PTW);

    // ---- Q fragment (B operand: [n=qrow][k=e]); fold scale*log2e ----
    const float qs = 0.125f * 1.44269504f;
    bf16x8 qf[2];
    {
        const int r = qt * 64 + wq * 16 + ln16;
        const float* qa = Q + (((size_t)b * Lq + r) * Hq + h) * Eq + quad * 8;
        #pragma unroll
        for (int ec = 0; ec < 2; ++ec) {
            float4 f0 = ((const float4*)(qa + ec * 32))[0];
            float4 f1 = ((const float4*)(qa + ec * 32))[1];
            f0.x*=qs; f0.y*=qs; f0.z*=qs; f0.w*=qs;
            f1.x*=qs; f1.y*=qs; f1.z*=qs; f1.w*=qs;
            qf[ec] = cvt8(f0, f1);
        }
    }

    floatx4 O[4];
    #pragma unroll
    for (int i = 0; i < 4; ++i) O[i] = (floatx4){0, 0, 0, 0};
    // finite sentinel (NOT -inf): an all-masked key-half must not produce inf-inf
    float m = -1e30f, l = 0.f;

    // prefetch registers (512 threads: 8 K-floats + 8 V-floats each)
    float4 kq[2];
    float  vq[8];
    const int kj = tid >> 3, kc = (tid & 7) * 8;   // K staging: row kj, cols kc..kc+7
    const int vd = tid & 63, vk = wv * 8;          // V staging: dim vd, keys vk..vk+7

    auto load_tile = [&](int kt) {
        const float* kb = Kp + (((size_t)b * Lq + kt * 64 + kj) * Hq + h) * Eq + kc;
        kq[0] = ((const float4*)kb)[0]; kq[1] = ((const float4*)kb)[1];
        const float* vb = Vp + (((size_t)b * Lq + kt * 64 + vk) * Hq + h) * Eq + vd;
        #pragma unroll
        for (int i = 0; i < 8; ++i) vq[i] = vb[(size_t)i * (Hq * Eq)];
    };

    load_tile(0);
    for (int kt = 0; kt <= qt; ++kt) {
        __syncthreads();   // all waves done reading previous tile
        *(bf16x8*)&k_lds[kj][kc] = cvt8(kq[0], kq[1]);
        {
            const float4* vq4 = (const float4*)vq;
            *(bf16x8*)&vt_lds[vd][vk] = cvt8(vq4[0], vq4[1]);
        }
        if (kt < qt) load_tile(kt + 1);   // prefetch overlaps with compute below
        __syncthreads();

        // fragment reads for this wave's key half
        bf16x8 kf[2][2], vf[4];
        #pragma unroll
        for (int c = 0; c < 2; ++c) {
            kf[c][0] = *(const bf16x8*)&k_lds[(kh * 2 + c) * 16 + ln16][quad * 8];
            kf[c][1] = *(const bf16x8*)&k_lds[(kh * 2 + c) * 16 + ln16][32 + quad * 8];
        }
        #pragma unroll
        for (int c = 0; c < 4; ++c)
            vf[c] = *(const bf16x8*)&vt_lds[c * 16 + ln16][kh * 32 + quad * 8];

        // S^T chunk (32 keys x 16 qrows): col(ln16)=qrow, row(quad*4+r)=key-in-half
        floatx4 s[2];
        #pragma unroll
        for (int nc = 0; nc < 2; ++nc) {
            floatx4 acc = (floatx4){0, 0, 0, 0};
            acc = __builtin_amdgcn_mfma_f32_16x16x32_bf16(kf[nc][0], qf[0], acc, 0, 0, 0);
            acc = __builtin_amdgcn_mfma_f32_16x16x32_bf16(kf[nc][1], qf[1], acc, 0, 0, 0);
            s[nc] = acc;
        }
        if (kt == qt) {
            const int rin = wq * 16 + ln16;
            #pragma unroll
            for (int nc = 0; nc < 2; ++nc)
                #pragma unroll
                for (int r = 0; r < 4; ++r)
                    if (kh * 32 + nc * 16 + quad * 4 + r > rin) s[nc][r] = -INFINITY;
        }
        // partial row max over this key half
        float mn = s[0][0];
        #pragma unroll
        for (int nc = 0; nc < 2; ++nc)
            #pragma unroll
            for (int r = 0; r < 4; ++r) mn = fmaxf(mn, s[nc][r]);
        mn = fmaxf(mn, __shfl_xor(mn, 16, 64));
        mn = fmaxf(mn, __shfl_xor(mn, 32, 64));
        mn = fmaxf(mn, m);                       // m >= -1e30 keeps mn finite
        const float alpha = __builtin_amdgcn_exp2f(m - mn);
        m = mn;
        float ps = 0.f;
        float pv[2][4];
        #pragma unroll
        for (int nc = 0; nc < 2; ++nc)
            #pragma unroll
            for (int r = 0; r < 4; ++r) {
                pv[nc][r] = __builtin_amdgcn_exp2f(s[nc][r] - mn);
                ps += pv[nc][r];
            }
        ps += __shfl_xor(ps, 16, 64);
        ps += __shfl_xor(ps, 32, 64);
        l = l * alpha + ps;
        #pragma unroll
        for (int dc = 0; dc < 4; ++dc) O[dc] *= alpha;
        // P^T -> per-wave LDS (2 x b64), then one b128 B-frag read
        #pragma unroll
        for (int nc = 0; nc < 2; ++nc) {
            bf16x4 pk;
            pk[0] = (bf16_t)pv[nc][0]; pk[1] = (bf16_t)pv[nc][1];
            pk[2] = (bf16_t)pv[nc][2]; pk[3] = (bf16_t)pv[nc][3];
            *(bf16x4*)&pt[ln16][nc * 16 + quad * 4] = pk;
        }
        bf16x8 pf = *(const bf16x8*)&pt[ln16][quad * 8];
        // O^T += V^T[:, key-half] P^T
        #pragma unroll
        for (int dc = 0; dc < 4; ++dc)
            O[dc] = __builtin_amdgcn_mfma_f32_16x16x32_bf16(vf[dc], pf, O[dc], 0, 0, 0);
    }

    // ---- merge key halves + epilogue (staging LDS is dead; alias it) ----
    __syncthreads();
    float* mb = (float*)smem;   // 4608 floats = 18432 B = exactly the staging area
    if (kh) {
        float* dst = mb + (wq * 64 + lane) * 18;
        #pragma unroll
        for (int dc = 0; dc < 4; ++dc) {
            *(float2*)(dst + dc * 4)     = make_float2(O[dc][0], O[dc][1]);
            *(float2*)(dst + dc * 4 + 2) = make_float2(O[dc][2], O[dc][3]);
        }
        dst[16] = m; dst[17] = l;
    }
    __syncthreads();
    if (!kh) {
        const float* src = mb + (wq * 64 + lane) * 18;
        const float m1 = src[16], l1 = src[17];
        const float mm = fmaxf(m, m1);
        const float a0 = __builtin_amdgcn_exp2f(m - mm);
        const float a1 = __builtin_amdgcn_exp2f(m1 - mm);
        const float inv = 1.0f / (l * a0 + l1 * a1);
        const int row = qt * 64 + wq * 16 + ln16;
        float* op = out + (((size_t)b * Lq + row) * Hq + slot) * Eq + quad * 4;
        #pragma unroll
        for (int dc = 0; dc < 4; ++dc) {
            float4 o;
            o.x = (O[dc][0] * a0 + src[dc * 4 + 0] * a1) * inv;
            o.y = (O[dc][1] * a0 + src[dc * 4 + 1] * a1) * inv;
            o.z = (O[dc][2] * a0 + src[dc * 4 + 2] * a1) * inv;
            o.w = (O[dc][3] * a0 + src[dc * 4 + 3] * a1) * inv;
            *(float4*)(op + dc * 16) = o;
        }
    }
}

extern "C" void kernel_launch(void* const* d_in, const int* in_sizes, int n_in,
                              void* d_out, int out_size, void* d_ws, size_t ws_size,
                              hipStream_t stream) {
    const float* queries = (const float*)d_in[0];
    const float* keys    = (const float*)d_in[1];
    const float* keysT   = (const float*)d_in[2];
    const float* values  = (const float*)d_in[3];
    const float* valuesT = (const float*)d_in[4];
    float* out = (float*)d_out;

    dim3 grid(Hq, 8, 16);   // (slot, batch, qtile): id%8==slot -> slot-per-XCD L2 grouping
    dim3 block(512);
    attn_mfma<<<grid, block, 0, stream>>>(queries, keys, keysT, values, valuesT, out);
}

// Round 4
// 132.536 us; speedup vs baseline: 1.6624x; 1.5573x over previous
//
#include <hip/hip_runtime.h>
#include <math.h>

#define Lq 1024
#define Hq 8
#define Eq 64
#define LDW 72   // staging row length (bf16 elems); 144 B rows stay 16B-aligned
#define PTW 40   // P^T row length (bf16 elems); 80 B rows, 16B-aligned

// slot -> source head: _PERM=[6,2,1,7,3,0,5,4]; slots 0..6 = series {2,1,7,3,0,5,4}, slot 7 = cross head 6
#define SRC_HEAD_PACKED 0x64503712u

typedef __bf16 bf16_t;
typedef __bf16 bf16x8 __attribute__((ext_vector_type(8)));
typedef __bf16 bf16x4 __attribute__((ext_vector_type(4)));
typedef float floatx4 __attribute__((ext_vector_type(4)));

__device__ __forceinline__ bf16x8 cvt8(const float4 a, const float4 b) {
    bf16x8 r;
    r[0] = (bf16_t)a.x; r[1] = (bf16_t)a.y; r[2] = (bf16_t)a.z; r[3] = (bf16_t)a.w;
    r[4] = (bf16_t)b.x; r[5] = (bf16_t)b.y; r[6] = (bf16_t)b.z; r[7] = (bf16_t)b.w;
    return r;
}

// 8 waves: wq = wv&3 -> q-row group (16 rows), kh = wv>>2 -> key half (32 keys).
// One q-tile per block; each wave keeps a partial online softmax over its key half.
// launch_bounds min-waves/EU = 4 (NOT 8): 8 shrinks the unified VGPR budget to 64
// and forces catastrophic scratch spills (R2/R3: VGPR=32, WRITE_SIZE 137-163 MB).
__global__ __launch_bounds__(512, 4)
void attn_mfma(const float* __restrict__ Q, const float* __restrict__ Ks,
               const float* __restrict__ KTs, const float* __restrict__ Vs,
               const float* __restrict__ VTs, float* __restrict__ out) {
    // grid = (slot, b, z): linear id % 8 == slot -> one slot per XCD -> K/V L2 reuse
    const int slot = blockIdx.x;
    const int b    = blockIdx.y;
    const int qt   = 15 - blockIdx.z;       // longest blocks dispatched first
    const int h    = (SRC_HEAD_PACKED >> (slot * 4)) & 0xF;
    const float* __restrict__ Kp = (slot == 7) ? KTs : Ks;
    const float* __restrict__ Vp = (slot == 7) ? VTs : Vs;

    const int tid  = threadIdx.x;
    const int wv   = tid >> 6;              // 0..7
    const int lane = tid & 63;
    const int ln16 = lane & 15;
    const int quad = lane >> 4;
    const int wq   = wv & 3;                // q-row group
    const int kh   = wv >> 2;               // key half

    __shared__ alignas(16) unsigned short smem[64 * LDW * 2 + 8 * 16 * PTW]; // 28672 B
    unsigned short (*k_lds)[LDW]  = (unsigned short (*)[LDW])smem;             // K[key][e]
    unsigned short (*vt_lds)[LDW] = (unsigned short (*)[LDW])(smem + 64 * LDW);// V^T[d][key]
    unsigned short (*pt)[PTW]     = (unsigned short (*)[PTW])(smem + 2 * 64 * LDW + wv * 16 * PTW);

    // ---- Q fragment (B operand: [n=qrow][k=e]); fold scale*log2e ----
    const float qs = 0.125f * 1.44269504f;
    bf16x8 qf[2];
    {
        const int r = qt * 64 + wq * 16 + ln16;
        const float* qa = Q + (((size_t)b * Lq + r) * Hq + h) * Eq + quad * 8;
        #pragma unroll
        for (int ec = 0; ec < 2; ++ec) {
            float4 f0 = ((const float4*)(qa + ec * 32))[0];
            float4 f1 = ((const float4*)(qa + ec * 32))[1];
            f0.x*=qs; f0.y*=qs; f0.z*=qs; f0.w*=qs;
            f1.x*=qs; f1.y*=qs; f1.z*=qs; f1.w*=qs;
            qf[ec] = cvt8(f0, f1);
        }
    }

    floatx4 O[4];
    #pragma unroll
    for (int i = 0; i < 4; ++i) O[i] = (floatx4){0, 0, 0, 0};
    // finite sentinel (NOT -inf): an all-masked key-half must not produce inf-inf
    float m = -1e30f, l = 0.f;

    // prefetch registers (512 threads: 8 K-floats + 8 V-floats each)
    float4 kq[2];
    float  vq[8];
    const int kj = tid >> 3, kc = (tid & 7) * 8;   // K staging: row kj, cols kc..kc+7
    const int vd = tid & 63, vk = wv * 8;          // V staging: dim vd, keys vk..vk+7

    auto load_tile = [&](int kt) {
        const float* kb = Kp + (((size_t)b * Lq + kt * 64 + kj) * Hq + h) * Eq + kc;
        kq[0] = ((const float4*)kb)[0]; kq[1] = ((const float4*)kb)[1];
        const float* vb = Vp + (((size_t)b * Lq + kt * 64 + vk) * Hq + h) * Eq + vd;
        #pragma unroll
        for (int i = 0; i < 8; ++i) vq[i] = vb[(size_t)i * (Hq * Eq)];
    };

    load_tile(0);
    for (int kt = 0; kt <= qt; ++kt) {
        __syncthreads();   // all waves done reading previous tile
        *(bf16x8*)&k_lds[kj][kc] = cvt8(kq[0], kq[1]);
        {
            const float4* vq4 = (const float4*)vq;
            *(bf16x8*)&vt_lds[vd][vk] = cvt8(vq4[0], vq4[1]);
        }
        if (kt < qt) load_tile(kt + 1);   // prefetch overlaps with compute below
        __syncthreads();

        // fragment reads for this wave's key half
        bf16x8 kf[2][2], vf[4];
        #pragma unroll
        for (int c = 0; c < 2; ++c) {
            kf[c][0] = *(const bf16x8*)&k_lds[(kh * 2 + c) * 16 + ln16][quad * 8];
            kf[c][1] = *(const bf16x8*)&k_lds[(kh * 2 + c) * 16 + ln16][32 + quad * 8];
        }
        #pragma unroll
        for (int c = 0; c < 4; ++c)
            vf[c] = *(const bf16x8*)&vt_lds[c * 16 + ln16][kh * 32 + quad * 8];

        // S^T chunk (32 keys x 16 qrows): col(ln16)=qrow, row(quad*4+r)=key-in-half
        floatx4 s[2];
        #pragma unroll
        for (int nc = 0; nc < 2; ++nc) {
            floatx4 acc = (floatx4){0, 0, 0, 0};
            acc = __builtin_amdgcn_mfma_f32_16x16x32_bf16(kf[nc][0], qf[0], acc, 0, 0, 0);
            acc = __builtin_amdgcn_mfma_f32_16x16x32_bf16(kf[nc][1], qf[1], acc, 0, 0, 0);
            s[nc] = acc;
        }
        if (kt == qt) {
            const int rin = wq * 16 + ln16;
            #pragma unroll
            for (int nc = 0; nc < 2; ++nc)
                #pragma unroll
                for (int r = 0; r < 4; ++r)
                    if (kh * 32 + nc * 16 + quad * 4 + r > rin) s[nc][r] = -INFINITY;
        }
        // partial row max over this key half
        float mn = s[0][0];
        #pragma unroll
        for (int nc = 0; nc < 2; ++nc)
            #pragma unroll
            for (int r = 0; r < 4; ++r) mn = fmaxf(mn, s[nc][r]);
        mn = fmaxf(mn, __shfl_xor(mn, 16, 64));
        mn = fmaxf(mn, __shfl_xor(mn, 32, 64));
        mn = fmaxf(mn, m);                       // m >= -1e30 keeps mn finite
        const float alpha = __builtin_amdgcn_exp2f(m - mn);
        m = mn;
        float ps = 0.f;
        float pv[2][4];
        #pragma unroll
        for (int nc = 0; nc < 2; ++nc)
            #pragma unroll
            for (int r = 0; r < 4; ++r) {
                pv[nc][r] = __builtin_amdgcn_exp2f(s[nc][r] - mn);
                ps += pv[nc][r];
            }
        ps += __shfl_xor(ps, 16, 64);
        ps += __shfl_xor(ps, 32, 64);
        l = l * alpha + ps;
        #pragma unroll
        for (int dc = 0; dc < 4; ++dc) O[dc] *= alpha;
        // P^T -> per-wave LDS (2 x b64), then one b128 B-frag read
        #pragma unroll
        for (int nc = 0; nc < 2; ++nc) {
            bf16x4 pk;
            pk[0] = (bf16_t)pv[nc][0]; pk[1] = (bf16_t)pv[nc][1];
            pk[2] = (bf16_t)pv[nc][2]; pk[3] = (bf16_t)pv[nc][3];
            *(bf16x4*)&pt[ln16][nc * 16 + quad * 4] = pk;
        }
        bf16x8 pf = *(const bf16x8*)&pt[ln16][quad * 8];
        // O^T += V^T[:, key-half] P^T
        #pragma unroll
        for (int dc = 0; dc < 4; ++dc)
            O[dc] = __builtin_amdgcn_mfma_f32_16x16x32_bf16(vf[dc], pf, O[dc], 0, 0, 0);
    }

    // ---- merge key halves + epilogue (staging LDS is dead; alias it) ----
    __syncthreads();
    float* mb = (float*)smem;   // 4608 floats = 18432 B = exactly the staging area
    if (kh) {
        float* dst = mb + (wq * 64 + lane) * 18;
        #pragma unroll
        for (int dc = 0; dc < 4; ++dc) {
            *(float2*)(dst + dc * 4)     = make_float2(O[dc][0], O[dc][1]);
            *(float2*)(dst + dc * 4 + 2) = make_float2(O[dc][2], O[dc][3]);
        }
        dst[16] = m; dst[17] = l;
    }
    __syncthreads();
    if (!kh) {
        const float* src = mb + (wq * 64 + lane) * 18;
        const float m1 = src[16], l1 = src[17];
        const float mm = fmaxf(m, m1);
        const float a0 = __builtin_amdgcn_exp2f(m - mm);
        const float a1 = __builtin_amdgcn_exp2f(m1 - mm);
        const float inv = 1.0f / (l * a0 + l1 * a1);
        const int row = qt * 64 + wq * 16 + ln16;
        float* op = out + (((size_t)b * Lq + row) * Hq + slot) * Eq + quad * 4;
        #pragma unroll
        for (int dc = 0; dc < 4; ++dc) {
            float4 o;
            o.x = (O[dc][0] * a0 + src[dc * 4 + 0] * a1) * inv;
            o.y = (O[dc][1] * a0 + src[dc * 4 + 1] * a1) * inv;
            o.z = (O[dc][2] * a0 + src[dc * 4 + 2] * a1) * inv;
            o.w = (O[dc][3] * a0 + src[dc * 4 + 3] * a1) * inv;
            *(float4*)(op + dc * 16) = o;
        }
    }
}

extern "C" void kernel_launch(void* const* d_in, const int* in_sizes, int n_in,
                              void* d_out, int out_size, void* d_ws, size_t ws_size,
                              hipStream_t stream) {
    const float* queries = (const float*)d_in[0];
    const float* keys    = (const float*)d_in[1];
    const float* keysT   = (const float*)d_in[2];
    const float* values  = (const float*)d_in[3];
    const float* valuesT = (const float*)d_in[4];
    float* out = (float*)d_out;

    dim3 grid(Hq, 8, 16);   // (slot, batch, qtile): id%8==slot -> slot-per-XCD L2 grouping
    dim3 block(512);
    attn_mfma<<<grid, block, 0, stream>>>(queries, keys, keysT, values, valuesT, out);
}